// Round 1
// baseline (157.575 us; speedup 1.0000x reference)
//
#include <hip/hip_runtime.h>

#define DD 512   // feature dim
#define H1 256   // hidden 1
#define H2 128   // hidden 2
#define CC 20    // classes
#define QB 4     // queries per block

// workspace float offsets
#define OFF_SUMF 0
#define OFF_B1C  (CC*DD)             // 10240
#define OFF_H10  (OFF_B1C + CC*H1)   // 15360
#define OFF_ST   (OFF_H10 + H1)      // 15616
#define NSTAT    (1 + 4*CC)          // dis0, dis_c, alpha_c, beta_c, gamma_c

// ---------------- Kernel A: class sums + degree stats ----------------
__global__ __launch_bounds__(256) void k_precompA(
    const float* __restrict__ Sf, const int* __restrict__ labels, int S,
    float* __restrict__ SumF, float* __restrict__ stats) {
  __shared__ int lab[128];
  int tid = threadIdx.x;
  if (tid < S) lab[tid] = labels[tid];
  __syncthreads();
  int b = blockIdx.x;
  if (b < CC) {
    for (int d = tid; d < DD; d += blockDim.x) {
      float acc = 0.f;
      for (int j = 0; j < S; ++j)
        if (lab[j] == b) acc += Sf[j * DD + d];
      SumF[b * DD + d] = acc;
    }
  } else if (tid < CC) {
    int cnt = 0;
    for (int j = 0; j < S; ++j) if (lab[j] == tid) cnt++;
    float deg = 1.f + (float)cnt;            // query link + same-class (incl self)
    float dis  = rsqrtf(deg + 1e-6f);
    float dis0 = rsqrtf((float)S + 1e-6f);
    stats[1 + tid]          = dis;                         // dis_c
    stats[1 + CC + tid]     = dis0 * dis;                  // alpha_c (h1 scale on u)
    stats[1 + 2*CC + tid]   = dis * dis * (float)cnt;      // beta_c  (P scale)
    stats[1 + 3*CC + tid]   = dis * (float)cnt;            // gamma_c (qe sum weight)
    if (tid == 0) stats[0] = dis0;
  }
}

// ---------------- Kernel B: B1c = (dis_c^2 * SumF_c) @ W1 + b1 ; h1_0 ----------------
__global__ __launch_bounds__(256) void k_precompB(
    const float* __restrict__ SumF, const float* __restrict__ W1,
    const float* __restrict__ b1, const float* __restrict__ stats,
    float* __restrict__ B1c, float* __restrict__ h10) {
  int b = blockIdx.x, tid = threadIdx.x;
  if (b < CC) {
    float dis = stats[1 + b];
    float sc = dis * dis;
    float acc = 0.f;
#pragma unroll 4
    for (int d = 0; d < DD; ++d) acc += SumF[b * DD + d] * W1[d * H1 + tid];
    B1c[b * H1 + tid] = b1[tid] + sc * acc;
  } else {
    __shared__ float row0[DD];
    float dis0 = stats[0];
    for (int d = tid; d < DD; d += 256) {
      float acc = 0.f;
#pragma unroll
      for (int c = 0; c < CC; ++c) acc += stats[1 + c] * SumF[c * DD + d];
      row0[d] = dis0 * acc;
    }
    __syncthreads();
    float acc = 0.f;
#pragma unroll 4
    for (int d = 0; d < DD; ++d) acc += row0[d] * W1[d * H1 + tid];
    h10[tid] = fmaxf(b1[tid] + acc, 0.f);
  }
}

// ---------------- Kernel C: per-query pipeline ----------------
__global__ __launch_bounds__(256) void k_query(
    const float* __restrict__ qf, const float* __restrict__ W1,
    const float* __restrict__ W2, const float* __restrict__ b2,
    const float* __restrict__ B1c, const float* __restrict__ h10,
    const float* __restrict__ stats, float* __restrict__ out, int Q) {
  __shared__ __align__(16) float qlds[QB][DD];
  __shared__ __align__(16) float ulds[QB][H1];
  __shared__ __align__(16) float h1[CC][H1];
  __shared__ float proto[CC][H2 + 1];   // +1 pad: conflict-free column reads
  __shared__ float g2[H2];
  __shared__ float qe[H2];
  __shared__ float psum[2][H2];
  __shared__ float h0l[H1];
  __shared__ float st[NSTAT];

  int tid = threadIdx.x;
  int q0 = blockIdx.x * QB;
  int nq = Q - q0; if (nq > QB) nq = QB;

  if (tid < NSTAT) st[tid] = stats[tid];
  h0l[tid] = h10[tid];  // tid < 256 == H1
  // load queries (coalesced float4)
  for (int i = tid; i < nq * (DD / 4); i += 256)
    ((float4*)qlds)[i] = ((const float4*)(qf + (size_t)q0 * DD))[i];
  __syncthreads();

  // g2 = h1_0 @ W2  (threads < H2)
  if (tid < H2) {
    float acc = 0.f;
#pragma unroll 4
    for (int j = 0; j < H1; ++j) acc += h0l[j] * W2[j * H2 + tid];
    g2[tid] = acc;
  }

  // phase 1: u[qq] = q[qq] @ W1 ; thread tid owns output column tid
  {
    float a0 = 0.f, a1 = 0.f, a2 = 0.f, a3 = 0.f;
    for (int d = 0; d < DD; d += 4) {
      float w0 = W1[(d + 0) * H1 + tid];
      float w1 = W1[(d + 1) * H1 + tid];
      float w2 = W1[(d + 2) * H1 + tid];
      float w3 = W1[(d + 3) * H1 + tid];
      float4 x0 = *(const float4*)&qlds[0][d];
      float4 x1 = *(const float4*)&qlds[1][d];
      float4 x2 = *(const float4*)&qlds[2][d];
      float4 x3 = *(const float4*)&qlds[3][d];
      a0 += x0.x * w0 + x0.y * w1 + x0.z * w2 + x0.w * w3;
      a1 += x1.x * w0 + x1.y * w1 + x1.z * w2 + x1.w * w3;
      a2 += x2.x * w0 + x2.y * w1 + x2.z * w2 + x2.w * w3;
      a3 += x3.x * w0 + x3.y * w1 + x3.z * w2 + x3.w * w3;
    }
    ulds[0][tid] = a0; ulds[1][tid] = a1; ulds[2][tid] = a2; ulds[3][tid] = a3;
  }
  __syncthreads();

  for (int qq = 0; qq < nq; ++qq) {
    // build h1_c = relu(alpha_c * u + B1c)
    for (int e = tid; e < CC * H1; e += 256) {
      int c = e >> 8, j = e & (H1 - 1);
      h1[c][j] = fmaxf(st[1 + CC + c] * ulds[qq][j] + B1c[e], 0.f);
    }
    __syncthreads();

    // P_c[k] = h1_c @ W2  ; 128 k-lanes x 2 groups of 10 classes
    int k = tid & (H2 - 1), s = tid >> 7;
    float acc[10];
#pragma unroll
    for (int i = 0; i < 10; ++i) acc[i] = 0.f;
    for (int j0 = 0; j0 < H1; j0 += 4) {
      float w0 = W2[(j0 + 0) * H2 + k];
      float w1 = W2[(j0 + 1) * H2 + k];
      float w2 = W2[(j0 + 2) * H2 + k];
      float w3 = W2[(j0 + 3) * H2 + k];
#pragma unroll
      for (int i = 0; i < 10; ++i) {
        int c = s * 10 + i;
        float4 h = *(const float4*)&h1[c][j0];
        acc[i] += h.x * w0 + h.y * w1 + h.z * w2 + h.w * w3;
      }
    }

    // protos + partial sum for q_emb
    {
      float part = 0.f;
      float b2k = b2[k], g2k = g2[k], d0 = st[0];
#pragma unroll
      for (int i = 0; i < 10; ++i) {
        int c = s * 10 + i;
        float P = acc[i];
        float pre = d0 * st[1 + c] * g2k + st[1 + 2 * CC + c] * P + b2k;
        proto[c][k] = fmaxf(pre, 0.f);
        part += st[1 + 3 * CC + c] * P;
      }
      psum[s][k] = part;
    }
    __syncthreads();
    if (tid < H2)
      qe[tid] = fmaxf(st[0] * (psum[0][tid] + psum[1][tid]) + b2[tid], 0.f);
    __syncthreads();

    // cosine similarity: one class per thread (proto padded -> conflict-free)
    if (tid < CC) {
      float num = 0.f, pn = 0.f, qn = 0.f;
#pragma unroll 4
      for (int k2 = 0; k2 < H2; ++k2) {
        float e_ = qe[k2];
        float p = proto[tid][k2];
        num += e_ * p; pn += p * p; qn += e_ * e_;
      }
      float denom = sqrtf(qn) * sqrtf(pn);
      out[(size_t)(q0 + qq) * CC + tid] = num / fmaxf(denom, 1e-8f);
    }
    __syncthreads();
  }
}

extern "C" void kernel_launch(void* const* d_in, const int* in_sizes, int n_in,
                              void* d_out, int out_size, void* d_ws, size_t ws_size,
                              hipStream_t stream) {
  const float* Sf     = (const float*)d_in[0];
  const int*   labels = (const int*)d_in[1];
  const float* qf     = (const float*)d_in[2];
  const float* W1     = (const float*)d_in[3];
  const float* b1     = (const float*)d_in[4];
  const float* W2     = (const float*)d_in[5];
  const float* b2     = (const float*)d_in[6];
  int S = in_sizes[1];
  int Q = in_sizes[2] / DD;

  float* ws    = (float*)d_ws;
  float* SumF  = ws + OFF_SUMF;
  float* B1c   = ws + OFF_B1C;
  float* h10   = ws + OFF_H10;
  float* stats = ws + OFF_ST;
  float* out   = (float*)d_out;

  hipLaunchKernelGGL(k_precompA, dim3(CC + 1), dim3(256), 0, stream, Sf, labels, S, SumF, stats);
  hipLaunchKernelGGL(k_precompB, dim3(CC + 1), dim3(H1), 0, stream, SumF, W1, b1, stats, B1c, h10);
  int nb = (Q + QB - 1) / QB;
  hipLaunchKernelGGL(k_query, dim3(nb), dim3(256), 0, stream, qf, W1, W2, b2, B1c, h10, stats, out, Q);
}

// Round 2
// 131.411 us; speedup vs baseline: 1.1991x; 1.1991x over previous
//
#include <hip/hip_runtime.h>

#define DD 512   // feature dim
#define H1 256   // hidden 1
#define H2 128   // hidden 2
#define CC 20    // real classes
#define CP 24    // padded classes (divisible by 8 groups * 3)
#define QU 8     // queries per block in k_u

// workspace float offsets
#define OFF_SUMF 0
#define OFF_B1C  (CC*DD)                 // 10240
#define OFF_H10  (OFF_B1C + CP*H1)       // 16384
#define OFF_PRE  (OFF_H10 + H1)          // 16640
#define OFF_ST   (OFF_PRE + CC*H2)       // 19200
#define NSTAT    (1 + 4*CP)              // 97: dis0, dis[24], alpha[24], beta[24], gamma[24]
#define OFF_U    19328

// ---------------- Kernel A: class sums + degree stats ----------------
__global__ __launch_bounds__(256) void k_precompA(
    const float* __restrict__ Sf, const int* __restrict__ labels, int S,
    float* __restrict__ SumF, float* __restrict__ stats) {
  __shared__ int lab[128];
  int tid = threadIdx.x;
  if (tid < S) lab[tid] = labels[tid];
  __syncthreads();
  int b = blockIdx.x;
  if (b < CC) {
    for (int d = tid; d < DD; d += 256) {
      float acc = 0.f;
      for (int j = 0; j < S; ++j)
        if (lab[j] == b) acc += Sf[j * DD + d];
      SumF[b * DD + d] = acc;
    }
  } else if (tid < CP) {
    int cnt = 0;
    for (int j = 0; j < S; ++j) if (lab[j] == tid) cnt++;
    float deg = 1.f + (float)cnt;            // query link + same-class (incl self)
    float dis  = rsqrtf(deg + 1e-6f);
    float dis0 = rsqrtf((float)S + 1e-6f);
    stats[1 + tid]          = dis;                       // dis_c
    stats[1 + CP + tid]     = dis0 * dis;                // alpha_c
    stats[1 + 2*CP + tid]   = dis * dis * (float)cnt;    // beta_c  (0 for pad)
    stats[1 + 3*CP + tid]   = dis * (float)cnt;          // gamma_c (0 for pad)
    if (tid == 0) stats[0] = dis0;
  }
}

// ---------------- Kernel B: B1c rows (+ zero pad rows) and h1_0 ----------------
__global__ __launch_bounds__(256) void k_precompB(
    const float* __restrict__ SumF, const float* __restrict__ W1,
    const float* __restrict__ b1, const float* __restrict__ stats,
    float* __restrict__ B1c, float* __restrict__ h10) {
  int b = blockIdx.x, tid = threadIdx.x;
  if (b < CC) {
    float dis = stats[1 + b];
    float sc = dis * dis;
    float acc = 0.f;
#pragma unroll 4
    for (int d = 0; d < DD; ++d) acc += SumF[b * DD + d] * W1[d * H1 + tid];
    B1c[b * H1 + tid] = b1[tid] + sc * acc;
  } else if (b < CP) {
    B1c[b * H1 + tid] = 0.f;   // pad rows -> h1 pad rows harmless
  } else {
    __shared__ float row0[DD];
    float dis0 = stats[0];
    for (int d = tid; d < DD; d += 256) {
      float acc = 0.f;
#pragma unroll
      for (int c = 0; c < CC; ++c) acc += stats[1 + c] * SumF[c * DD + d];
      row0[d] = dis0 * acc;
    }
    __syncthreads();
    float acc = 0.f;
#pragma unroll 4
    for (int d = 0; d < DD; ++d) acc += row0[d] * W1[d * H1 + tid];
    h10[tid] = fmaxf(b1[tid] + acc, 0.f);
  }
}

// ---------------- Kernel P: pre_ck[c][k] = dis0*dis_c*(h1_0@W2)[k] + b2[k] ----------------
__global__ __launch_bounds__(128) void k_pre(
    const float* __restrict__ h10, const float* __restrict__ W2,
    const float* __restrict__ b2, const float* __restrict__ stats,
    float* __restrict__ pre) {
  int k = threadIdx.x;
  float g = 0.f;
#pragma unroll 4
  for (int j = 0; j < H1; ++j) g += h10[j] * W2[j * H2 + k];
  float d0 = stats[0], bb = b2[k];
#pragma unroll
  for (int c = 0; c < CC; ++c) pre[c * H2 + k] = d0 * stats[1 + c] * g + bb;
}

// ---------------- Kernel U: U[q][j] = qf[q] @ W1 (8 queries/block) ----------------
__global__ __launch_bounds__(256) void k_u(
    const float* __restrict__ qf, const float* __restrict__ W1,
    float* __restrict__ U, int Q) {
  int tid = threadIdx.x;
  int q0 = blockIdx.x * QU;
  int nq = Q - q0; if (nq > QU) nq = QU;
  float acc[QU];
#pragma unroll
  for (int i = 0; i < QU; ++i) acc[i] = 0.f;
  if (nq == QU) {
    for (int d = 0; d < DD; ++d) {
      float w = W1[d * H1 + tid];
#pragma unroll
      for (int i = 0; i < QU; ++i)
        acc[i] += qf[(size_t)(q0 + i) * DD + d] * w;   // q value wave-uniform -> s_load
    }
#pragma unroll
    for (int i = 0; i < QU; ++i) U[(size_t)(q0 + i) * H1 + tid] = acc[i];
  } else {
    for (int d = 0; d < DD; ++d) {
      float w = W1[d * H1 + tid];
#pragma unroll
      for (int i = 0; i < QU; ++i)
        if (i < nq) acc[i] += qf[(size_t)(q0 + i) * DD + d] * w;
    }
#pragma unroll
    for (int i = 0; i < QU; ++i)
      if (i < nq) U[(size_t)(q0 + i) * H1 + tid] = acc[i];
  }
}

// ---------------- Kernel Q: one query per block ----------------
template<bool UIN>
__global__ __launch_bounds__(256, 4) void k_query(
    const float* __restrict__ qf, const float* __restrict__ W1,
    const float* __restrict__ W2, const float* __restrict__ b2,
    const float* __restrict__ B1c, const float* __restrict__ pre_ck,
    const float* __restrict__ stats, const float* __restrict__ U,
    float* __restrict__ out, int Q) {
  __shared__ __align__(16) float h1[CP][H1];        // 24 KB
  __shared__ __align__(16) float proto[CC][H2 + 4]; // 10.3 KB, +4 pad
  __shared__ __align__(16) float psum[8][H2];       // 4 KB
  __shared__ float qe[H2];
  __shared__ float stc[NSTAT];

  int tid = threadIdx.x;
  int q = blockIdx.x;

  if (tid < NSTAT) stc[tid] = stats[tid];

  float uv;
  if constexpr (UIN) {
    uv = U[(size_t)q * H1 + tid];
  } else {
    float acc = 0.f;
    for (int d = 0; d < DD; ++d) acc += qf[(size_t)q * DD + d] * W1[d * H1 + tid];
    uv = acc;
  }
  __syncthreads();   // stc ready

  // h1[r][tid] = relu(alpha_r * u[tid] + B1c[r][tid]); thread owns column tid
#pragma unroll
  for (int r = 0; r < CP; ++r)
    h1[r][tid] = fmaxf(stc[1 + CP + r] * uv + B1c[r * H1 + tid], 0.f);
  __syncthreads();

  // P_c[k] = h1_c @ W2 : 8 groups x 3 classes, 4 contiguous k per thread
  int sg = tid >> 5, kq = tid & 31, k4 = kq * 4, cb = sg * 3;
  float a[3][4];
#pragma unroll
  for (int i = 0; i < 3; ++i)
#pragma unroll
    for (int kk = 0; kk < 4; ++kk) a[i][kk] = 0.f;

  const float4* __restrict__ W2v = (const float4*)W2;
#pragma unroll 2
  for (int j0 = 0; j0 < H1; j0 += 4) {
    float w[4][4], hh[3][4];
#pragma unroll
    for (int jj = 0; jj < 4; ++jj) {
      float4 t = W2v[(j0 + jj) * (H2 / 4) + kq];
      w[jj][0] = t.x; w[jj][1] = t.y; w[jj][2] = t.z; w[jj][3] = t.w;
    }
#pragma unroll
    for (int i = 0; i < 3; ++i) {
      float4 t = *(const float4*)&h1[cb + i][j0];   // 2 distinct rows/wave: free
      hh[i][0] = t.x; hh[i][1] = t.y; hh[i][2] = t.z; hh[i][3] = t.w;
    }
#pragma unroll
    for (int i = 0; i < 3; ++i)
#pragma unroll
      for (int jj = 0; jj < 4; ++jj)
#pragma unroll
        for (int kk = 0; kk < 4; ++kk)
          a[i][kk] = fmaf(hh[i][jj], w[jj][kk], a[i][kk]);
  }

  // epilogue: protos + q_emb partial sums
  __align__(16) float part[4] = {0.f, 0.f, 0.f, 0.f};
#pragma unroll
  for (int i = 0; i < 3; ++i) {
    int c = cb + i;
    float gam = stc[1 + 3 * CP + c];   // 0 for pad classes
#pragma unroll
    for (int kk = 0; kk < 4; ++kk) part[kk] += gam * a[i][kk];
    if (c < CC) {
      float bet = stc[1 + 2 * CP + c];
      float4 pre = *(const float4*)&pre_ck[c * H2 + k4];
      float4 pr;
      pr.x = fmaxf(pre.x + bet * a[i][0], 0.f);
      pr.y = fmaxf(pre.y + bet * a[i][1], 0.f);
      pr.z = fmaxf(pre.z + bet * a[i][2], 0.f);
      pr.w = fmaxf(pre.w + bet * a[i][3], 0.f);
      *(float4*)&proto[c][k4] = pr;
    }
  }
  *(float4*)&psum[sg][k4] = *(const float4*)part;
  __syncthreads();

  if (tid < H2) {
    float s = 0.f;
#pragma unroll
    for (int g = 0; g < 8; ++g) s += psum[g][tid];
    qe[tid] = fmaxf(stc[0] * s + b2[tid], 0.f);
  }
  __syncthreads();

  // cosine: 20 classes x 8-lane groups
  if (tid < 160) {
    int c = tid >> 3, l = tid & 7;
    float num = 0.f, pn = 0.f, qn = 0.f;
#pragma unroll
    for (int i = 0; i < 16; ++i) {
      int k = l + 8 * i;
      float e = qe[k], p = proto[c][k];
      num = fmaf(e, p, num); pn = fmaf(p, p, pn); qn = fmaf(e, e, qn);
    }
    num += __shfl_xor(num, 1); pn += __shfl_xor(pn, 1); qn += __shfl_xor(qn, 1);
    num += __shfl_xor(num, 2); pn += __shfl_xor(pn, 2); qn += __shfl_xor(qn, 2);
    num += __shfl_xor(num, 4); pn += __shfl_xor(pn, 4); qn += __shfl_xor(qn, 4);
    if (l == 0)
      out[(size_t)q * CC + c] = num / fmaxf(sqrtf(qn) * sqrtf(pn), 1e-8f);
  }
}

extern "C" void kernel_launch(void* const* d_in, const int* in_sizes, int n_in,
                              void* d_out, int out_size, void* d_ws, size_t ws_size,
                              hipStream_t stream) {
  const float* Sf     = (const float*)d_in[0];
  const int*   labels = (const int*)d_in[1];
  const float* qf     = (const float*)d_in[2];
  const float* W1     = (const float*)d_in[3];
  const float* b1     = (const float*)d_in[4];
  const float* W2     = (const float*)d_in[5];
  const float* b2     = (const float*)d_in[6];
  int S = in_sizes[1];
  int Q = in_sizes[2] / DD;

  float* ws    = (float*)d_ws;
  float* SumF  = ws + OFF_SUMF;
  float* B1c   = ws + OFF_B1C;
  float* h10   = ws + OFF_H10;
  float* pre   = ws + OFF_PRE;
  float* stats = ws + OFF_ST;
  float* Uptr  = ws + OFF_U;
  float* out   = (float*)d_out;

  bool useU = ws_size >= (size_t)(OFF_U + (size_t)Q * H1) * sizeof(float);

  k_precompA<<<dim3(CC + 1), dim3(256), 0, stream>>>(Sf, labels, S, SumF, stats);
  k_precompB<<<dim3(CP + 1), dim3(256), 0, stream>>>(SumF, W1, b1, stats, B1c, h10);
  k_pre<<<dim3(1), dim3(H2), 0, stream>>>(h10, W2, b2, stats, pre);
  if (useU) {
    k_u<<<dim3((Q + QU - 1) / QU), dim3(256), 0, stream>>>(qf, W1, Uptr, Q);
    k_query<true><<<dim3(Q), dim3(256), 0, stream>>>(qf, W1, W2, b2, B1c, pre, stats, Uptr, out, Q);
  } else {
    k_query<false><<<dim3(Q), dim3(256), 0, stream>>>(qf, W1, W2, b2, B1c, pre, stats, Uptr, out, Q);
  }
}